// Round 1
// baseline (5409.628 us; speedup 1.0000x reference)
//
#include <hip/hip_runtime.h>
#include <hip/hip_bf16.h>

#define N_QUERIES 16384
#define DIM 64
#define K_CODES 8192

#define QT 64    // queries per block (argmin kernel)
#define KT 128   // codebook rows per chunk
#define PAD 68   // LDS row stride in floats (bank-spread, 16B-aligned)

// ---------------------------------------------------------------------------
// Kernel 1: per-row squared norms of the codebook, f32.
// ---------------------------------------------------------------------------
__global__ __launch_bounds__(256) void wsq_kernel(const float* __restrict__ w,
                                                  float* __restrict__ wsq) {
    int k = blockIdx.x * 256 + threadIdx.x;   // 32 blocks * 256 = 8192
    const float4* w4 = reinterpret_cast<const float4*>(w + (size_t)k * DIM);
    float s = 0.f;
#pragma unroll
    for (int i = 0; i < DIM / 4; ++i) {
        float4 v = w4[i];
        s = fmaf(v.x, v.x, s);
        s = fmaf(v.y, v.y, s);
        s = fmaf(v.z, v.z, s);
        s = fmaf(v.w, v.w, s);
    }
    wsq[k] = s;
}

// ---------------------------------------------------------------------------
// Kernel 2: argmin_k ( wsq[k] - 2 * x.w[k] ) per query.
// f32 main pass with per-thread top-2 tracking, then f64 rescore of the
// candidates (exact vs a float64 reference), earliest-index tie-break.
// One block per 64-query tile, full K sweep (no cross-block merge).
// ---------------------------------------------------------------------------
__global__ __launch_bounds__(256) void argmin_kernel(
    const float* __restrict__ x, const float* __restrict__ w,
    const float* __restrict__ wsq, int* __restrict__ out_idx) {

    __shared__ float xs[QT][PAD];                       // 17408 B
    __shared__ __align__(16) char smem2[KT * PAD * 4];  // 34816 B, reused

    float (*wl)[PAD]   = reinterpret_cast<float (*)[PAD]>(smem2);
    double (*redv)[32] = reinterpret_cast<double (*)[32]>(smem2);        // 16384 B
    int (*redi)[32]    = reinterpret_cast<int (*)[32]>(smem2 + QT * 32 * 8); // 8192 B

    const int t  = threadIdx.x;
    const int ng = t & 31;   // codebook-column group 0..31
    const int mg = t >> 5;   // query-row group    0..7
    const int qb = blockIdx.x * QT;

    // ---- stage the x tile: 64 rows x 64 cols, 4 float4 per thread ----
    {
        const float4* xg = reinterpret_cast<const float4*>(x + (size_t)qb * DIM);
#pragma unroll
        for (int i = 0; i < 4; ++i) {
            int f = i * 256 + t;                 // 0..1023
            float4 v = xg[f];
            *reinterpret_cast<float4*>(&xs[f >> 4][(f & 15) * 4]) = v;
        }
    }

    // per-thread top-2 per owned query row (rows m = i*8 + mg)
    float v1[8], v2[8];
    int   i1[8], i2[8];
#pragma unroll
    for (int i = 0; i < 8; ++i) { v1[i] = 3.0e38f; v2[i] = 3.0e38f; i1[i] = 0; i2[i] = 0; }

    const float4* wg = reinterpret_cast<const float4*>(w);
    float4 pre[8];
#pragma unroll
    for (int i = 0; i < 8; ++i) pre[i] = wg[i * 256 + t];   // chunk 0 prefetch

    const int NCHUNK = K_CODES / KT;   // 64
    for (int c = 0; c < NCHUNK; ++c) {
        __syncthreads();   // protect wl from previous iteration's readers
#pragma unroll
        for (int i = 0; i < 8; ++i) {
            int f = i * 256 + t;                 // 0..2047
            *reinterpret_cast<float4*>(&wl[f >> 4][(f & 15) * 4]) = pre[i];
        }
        __syncthreads();
        if (c + 1 < NCHUNK) {
#pragma unroll
            for (int i = 0; i < 8; ++i)
                pre[i] = wg[(size_t)(c + 1) * (KT * 16) + i * 256 + t];
        }

        float acc[8][4];
#pragma unroll
        for (int i = 0; i < 8; ++i)
#pragma unroll
            for (int j = 0; j < 4; ++j) acc[i][j] = 0.f;

#pragma unroll
        for (int d = 0; d < DIM; d += 4) {
            float4 xv[8], wv[4];
#pragma unroll
            for (int i = 0; i < 8; ++i)
                xv[i] = *reinterpret_cast<const float4*>(&xs[i * 8 + mg][d]);
#pragma unroll
            for (int j = 0; j < 4; ++j)
                wv[j] = *reinterpret_cast<const float4*>(&wl[j * 32 + ng][d]);
#pragma unroll
            for (int i = 0; i < 8; ++i)
#pragma unroll
                for (int j = 0; j < 4; ++j) {
                    acc[i][j] = fmaf(xv[i].x, wv[j].x, acc[i][j]);
                    acc[i][j] = fmaf(xv[i].y, wv[j].y, acc[i][j]);
                    acc[i][j] = fmaf(xv[i].z, wv[j].z, acc[i][j]);
                    acc[i][j] = fmaf(xv[i].w, wv[j].w, acc[i][j]);
                }
        }

        // scores + top-2 update (k increases monotonically per thread: c, then j)
#pragma unroll
        for (int j = 0; j < 4; ++j) {
            int k = c * KT + j * 32 + ng;
            float w2 = wsq[k];
#pragma unroll
            for (int i = 0; i < 8; ++i) {
                float s = fmaf(-2.f, acc[i][j], w2);
                bool b1 = s < v1[i];
                bool b2 = s < v2[i];
                v2[i] = b1 ? v1[i] : (b2 ? s : v2[i]);
                i2[i] = b1 ? i1[i] : (b2 ? k : i2[i]);
                v1[i] = b1 ? s : v1[i];
                i1[i] = b1 ? k : i1[i];
            }
        }
    }

    __syncthreads();   // wl is dead; smem2 becomes the reduction buffer

    // ---- f64 rescore of both candidates; keep the better per thread ----
#pragma unroll 1
    for (int i = 0; i < 8; ++i) {
        int m = i * 8 + mg;
        double bv = 1e300;
        int    bi = 0x7fffffff;
#pragma unroll 1
        for (int cnd = 0; cnd < 2; ++cnd) {
            int k = (cnd == 0) ? i1[i] : i2[i];
            const float* wr = w + (size_t)k * DIM;
            double dot = 0.0, w2 = 0.0;
#pragma unroll
            for (int d = 0; d < DIM; d += 4) {
                float4 wv = *reinterpret_cast<const float4*>(wr + d);
                float4 xv = *reinterpret_cast<const float4*>(&xs[m][d]);
                dot += (double)xv.x * (double)wv.x + (double)xv.y * (double)wv.y
                     + (double)xv.z * (double)wv.z + (double)xv.w * (double)wv.w;
                w2  += (double)wv.x * (double)wv.x + (double)wv.y * (double)wv.y
                     + (double)wv.z * (double)wv.z + (double)wv.w * (double)wv.w;
            }
            double s = w2 - 2.0 * dot;
            if (s < bv || (s == bv && k < bi)) { bv = s; bi = k; }
        }
        redv[m][ng] = bv;
        redi[m][ng] = bi;
    }
    __syncthreads();

    // ---- final per-query argmin over the 32 thread-candidates ----
    if (t < QT) {
        double bv = redv[t][0];
        int    bi = redi[t][0];
#pragma unroll 1
        for (int s = 1; s < 32; ++s) {
            double v = redv[t][s];
            int    ii = redi[t][s];
            if (v < bv || (v == bv && ii < bi)) { bv = v; bi = ii; }
        }
        out_idx[qb + t] = bi;
    }
}

// ---------------------------------------------------------------------------
// Kernel 3: gather codebook rows, write quantized_st (= x + (q - x), matching
// the reference's f32 straight-through arithmetic), write indices as float,
// and accumulate per-block f64 partial sums of (q - x)^2.
// ---------------------------------------------------------------------------
__global__ __launch_bounds__(256) void gather_kernel(
    const float* __restrict__ x, const float* __restrict__ w,
    const int* __restrict__ idxbuf, float* __restrict__ out_q,
    float* __restrict__ out_idx_f, double* __restrict__ partials) {

    __shared__ double sred[4];
    int t  = threadIdx.x;
    int f4 = blockIdx.x * 256 + t;   // float4 index, 1024 blocks -> 262144 total
    int q  = f4 >> 4;                // 16 float4 per query row
    int c4 = f4 & 15;

    int k = idxbuf[q];
    float4 wv = reinterpret_cast<const float4*>(w)[k * 16 + c4];
    float4 xv = reinterpret_cast<const float4*>(x)[f4];

    float4 st;
    st.x = xv.x + (wv.x - xv.x);
    st.y = xv.y + (wv.y - xv.y);
    st.z = xv.z + (wv.z - xv.z);
    st.w = xv.w + (wv.w - xv.w);
    reinterpret_cast<float4*>(out_q)[f4] = st;

    if (c4 == 0) out_idx_f[q] = (float)k;

    double dx = (double)wv.x - (double)xv.x;
    double dy = (double)wv.y - (double)xv.y;
    double dz = (double)wv.z - (double)xv.z;
    double dw = (double)wv.w - (double)xv.w;
    double dsum = dx * dx + dy * dy + dz * dz + dw * dw;

#pragma unroll
    for (int off = 32; off; off >>= 1) dsum += __shfl_down(dsum, off);
    if ((t & 63) == 0) sred[t >> 6] = dsum;
    __syncthreads();
    if (t == 0) partials[blockIdx.x] = sred[0] + sred[1] + sred[2] + sred[3];
}

// ---------------------------------------------------------------------------
// Kernel 4: reduce partials -> loss = 1.25 * mean((q - x)^2)
// ---------------------------------------------------------------------------
__global__ __launch_bounds__(256) void loss_kernel(const double* __restrict__ partials,
                                                   float* __restrict__ out_loss) {
    __shared__ double sred[4];
    int t = threadIdx.x;
    double s = partials[t] + partials[t + 256] + partials[t + 512] + partials[t + 768];
#pragma unroll
    for (int off = 32; off; off >>= 1) s += __shfl_down(s, off);
    if ((t & 63) == 0) sred[t >> 6] = s;
    __syncthreads();
    if (t == 0) {
        double tot = sred[0] + sred[1] + sred[2] + sred[3];
        out_loss[0] = (float)(1.25 * tot / (double)(N_QUERIES * DIM));
    }
}

// ---------------------------------------------------------------------------
extern "C" void kernel_launch(void* const* d_in, const int* in_sizes, int n_in,
                              void* d_out, int out_size, void* d_ws, size_t ws_size,
                              hipStream_t stream) {
    const float* x = (const float*)d_in[0];   // inputs [16,32,32,64] f32
    const float* w = (const float*)d_in[1];   // weight [8192,64] f32
    float* out = (float*)d_out;

    char* ws = (char*)d_ws;
    float*  wsq      = (float*)ws;                       // 32 KB
    int*    idxbuf   = (int*)(ws + 32768);               // 64 KB
    double* partials = (double*)(ws + 32768 + 65536);    // 8 KB

    hipLaunchKernelGGL(wsq_kernel,    dim3(K_CODES / 256), dim3(256), 0, stream, w, wsq);
    hipLaunchKernelGGL(argmin_kernel, dim3(N_QUERIES / QT), dim3(256), 0, stream,
                       x, w, wsq, idxbuf);
    hipLaunchKernelGGL(gather_kernel, dim3(N_QUERIES * DIM / 1024), dim3(256), 0, stream,
                       x, w, idxbuf, out + 1, out + 1 + (size_t)N_QUERIES * DIM, partials);
    hipLaunchKernelGGL(loss_kernel,   dim3(1), dim3(256), 0, stream, partials, out);
}

// Round 2
// 549.772 us; speedup vs baseline: 9.8398x; 9.8398x over previous
//
#include <hip/hip_runtime.h>
#include <hip/hip_bf16.h>

#define N_QUERIES 16384
#define DIM 64
#define K_CODES 8192

#define QT 32                     // queries per block (argmin kernel)
#define KT 64                     // codebook rows per LDS chunk
#define NCHUNK (K_CODES / KT)     // 128

// ---------------------------------------------------------------------------
// async global -> LDS, 16 B per lane. LDS dest is wave-uniform base + lane*16.
// ---------------------------------------------------------------------------
__device__ __forceinline__ void gll16(const void* g, void* l) {
    __builtin_amdgcn_global_load_lds(
        (const __attribute__((address_space(1))) void*)g,
        (__attribute__((address_space(3))) void*)l, 16, 0, 0);
}

// ---------------------------------------------------------------------------
// Kernel 1: per-row squared norms of the codebook, f32.
// ---------------------------------------------------------------------------
__global__ __launch_bounds__(256) void wsq_kernel(const float* __restrict__ w,
                                                  float* __restrict__ wsq) {
    int k = blockIdx.x * 256 + threadIdx.x;   // 32 blocks * 256 = 8192
    const float4* w4 = reinterpret_cast<const float4*>(w + (size_t)k * DIM);
    float s = 0.f;
#pragma unroll
    for (int i = 0; i < DIM / 4; ++i) {
        float4 v = w4[i];
        s = fmaf(v.x, v.x, s);
        s = fmaf(v.y, v.y, s);
        s = fmaf(v.z, v.z, s);
        s = fmaf(v.w, v.w, s);
    }
    wsq[k] = s;
}

// ---------------------------------------------------------------------------
// Kernel 2: argmin_k ( wsq[k] - 2 * x.w[k] ) per query.
// f32 main pass (global_load_lds double-buffered w chunks, XOR-swizzled LDS)
// with per-thread top-2 tracking, then f64 rescore of the candidates,
// earliest-index tie-break. One block per 32-query tile, full K sweep.
// ---------------------------------------------------------------------------
__global__ __launch_bounds__(256) void argmin_kernel(
    const float* __restrict__ x, const float* __restrict__ w,
    const float* __restrict__ wsq, int* __restrict__ out_idx) {

    __shared__ __align__(256) float xs[QT * DIM];        // 8 KB, linear
    __shared__ __align__(256) float wbuf[2][KT * DIM];   // 32 KB, swizzled

    const int t  = threadIdx.x;
    const int l  = t & 63;    // lane
    const int ng = t & 31;    // codebook-column group 0..31
    const int mg = t >> 5;    // query-row group    0..7
    const int qb = blockIdx.x * QT;

    // ---- prologue: stage x tile (512 slots) + chunk 0 of w ----
    {
        const float* xg = x + (size_t)qb * DIM;
#pragma unroll
        for (int i = 0; i < 2; ++i) {
            int SB = i * 256 + (t & 192);        // wave-uniform slot base
            int L  = SB + l;                     // 0..511 (slot = 16 B)
            gll16(xg + (size_t)L * 4, (char*)xs + (size_t)SB * 16);
        }
    }
    {
#pragma unroll
        for (int i = 0; i < 4; ++i) {
            int SB  = i * 256 + (t & 192);
            int L   = SB + l;                    // 0..1023
            int row = L >> 4;
            int sg  = (L & 15) ^ (row & 7);      // pre-swizzled global slot
            gll16(w + (size_t)row * DIM + (size_t)sg * 4,
                  (char*)wbuf[0] + (size_t)SB * 16);
        }
    }
    asm volatile("s_waitcnt vmcnt(0)" ::: "memory");
    __syncthreads();

    // per-thread top-2 per owned query row (rows m = i*8 + mg, i = 0..3)
    float v1[4], v2[4];
    int   i1[4], i2[4];
#pragma unroll
    for (int i = 0; i < 4; ++i) { v1[i] = 3.0e38f; v2[i] = 3.0e38f; i1[i] = 0; i2[i] = 0; }

    const int xm4 = (ng & 7) << 4;               // swizzle XOR, byte units

    for (int c = 0; c < NCHUNK; ++c) {
        const float* wl = wbuf[c & 1];

        // issue next chunk's loads; they stay in flight during compute
        if (c + 1 < NCHUNK) {
            const float* wc = w + (size_t)(c + 1) * KT * DIM;
            float* dst = wbuf[(c + 1) & 1];
#pragma unroll
            for (int i = 0; i < 4; ++i) {
                int SB  = i * 256 + (t & 192);
                int L   = SB + l;
                int row = L >> 4;
                int sg  = (L & 15) ^ (row & 7);
                gll16(wc + (size_t)row * DIM + (size_t)sg * 4,
                      (char*)dst + (size_t)SB * 16);
            }
        }

        float acc[4][2];
#pragma unroll
        for (int i = 0; i < 4; ++i) { acc[i][0] = 0.f; acc[i][1] = 0.f; }

        // base byte addresses with the XOR fold (wbuf row offsets are
        // 256-aligned, xm4 occupies bits 4..6, d*4 occupies bits 4..7)
        uintptr_t wb0 = (uintptr_t)&wl[(0 * 32 + ng) * DIM] + xm4;
        uintptr_t wb1 = (uintptr_t)&wl[(1 * 32 + ng) * DIM] + xm4;
        const float* xr0 = &xs[(0 * 8 + mg) * DIM];
        const float* xr1 = &xs[(1 * 8 + mg) * DIM];
        const float* xr2 = &xs[(2 * 8 + mg) * DIM];
        const float* xr3 = &xs[(3 * 8 + mg) * DIM];

#pragma unroll 4
        for (int d = 0; d < DIM; d += 4) {
            float4 xv[4], wv[2];
            xv[0] = *reinterpret_cast<const float4*>(xr0 + d);
            xv[1] = *reinterpret_cast<const float4*>(xr1 + d);
            xv[2] = *reinterpret_cast<const float4*>(xr2 + d);
            xv[3] = *reinterpret_cast<const float4*>(xr3 + d);
            wv[0] = *reinterpret_cast<const float4*>(wb0 ^ (uintptr_t)(d << 2));
            wv[1] = *reinterpret_cast<const float4*>(wb1 ^ (uintptr_t)(d << 2));
#pragma unroll
            for (int i = 0; i < 4; ++i)
#pragma unroll
                for (int j = 0; j < 2; ++j) {
                    acc[i][j] = fmaf(xv[i].x, wv[j].x, acc[i][j]);
                    acc[i][j] = fmaf(xv[i].y, wv[j].y, acc[i][j]);
                    acc[i][j] = fmaf(xv[i].z, wv[j].z, acc[i][j]);
                    acc[i][j] = fmaf(xv[i].w, wv[j].w, acc[i][j]);
                }
        }

        // scores + top-2 update (k increases monotonically per thread)
#pragma unroll
        for (int j = 0; j < 2; ++j) {
            int k = c * KT + j * 32 + ng;
            float w2 = wsq[k];
#pragma unroll
            for (int i = 0; i < 4; ++i) {
                float s = fmaf(-2.f, acc[i][j], w2);
                bool b1 = s < v1[i];
                bool b2 = s < v2[i];
                v2[i] = b1 ? v1[i] : (b2 ? s : v2[i]);
                i2[i] = b1 ? i1[i] : (b2 ? k : i2[i]);
                v1[i] = b1 ? s : v1[i];
                i1[i] = b1 ? k : i1[i];
            }
        }

        asm volatile("s_waitcnt vmcnt(0)" ::: "memory");
        __syncthreads();   // next chunk staged; all reads of old buffer done
    }

    // ---- wbuf is dead; reuse as the reduction buffer ----
    double (*redv)[32] = reinterpret_cast<double (*)[32]>(&wbuf[0][0]);   // 8 KB
    int    (*redi)[32] = reinterpret_cast<int    (*)[32]>((char*)&wbuf[0][0] + QT * 32 * 8);

    // ---- f64 rescore of both candidates; keep the better per thread ----
#pragma unroll 1
    for (int i = 0; i < 4; ++i) {
        int m = i * 8 + mg;
        double bv = 1e300;
        int    bi = 0x7fffffff;
#pragma unroll 1
        for (int cnd = 0; cnd < 2; ++cnd) {
            int k = (cnd == 0) ? i1[i] : i2[i];
            const float* wr = w + (size_t)k * DIM;
            double dot = 0.0, w2 = 0.0;
#pragma unroll
            for (int d = 0; d < DIM; d += 4) {
                float4 wv = *reinterpret_cast<const float4*>(wr + d);
                float4 xv = *reinterpret_cast<const float4*>(&xs[m * DIM + d]);
                dot += (double)xv.x * (double)wv.x + (double)xv.y * (double)wv.y
                     + (double)xv.z * (double)wv.z + (double)xv.w * (double)wv.w;
                w2  += (double)wv.x * (double)wv.x + (double)wv.y * (double)wv.y
                     + (double)wv.z * (double)wv.z + (double)wv.w * (double)wv.w;
            }
            double s = w2 - 2.0 * dot;
            if (s < bv || (s == bv && k < bi)) { bv = s; bi = k; }
        }
        redv[m][ng] = bv;
        redi[m][ng] = bi;
    }
    __syncthreads();

    // ---- final per-query argmin over the 32 thread-candidates ----
    if (t < QT) {
        double bv = redv[t][0];
        int    bi = redi[t][0];
#pragma unroll 1
        for (int s = 1; s < 32; ++s) {
            double v  = redv[t][s];
            int    ii = redi[t][s];
            if (v < bv || (v == bv && ii < bi)) { bv = v; bi = ii; }
        }
        out_idx[qb + t] = bi;
    }
}

// ---------------------------------------------------------------------------
// Kernel 3: gather codebook rows, write quantized_st, write indices as float,
// accumulate per-block f64 partial sums of (q - x)^2.
// ---------------------------------------------------------------------------
__global__ __launch_bounds__(256) void gather_kernel(
    const float* __restrict__ x, const float* __restrict__ w,
    const int* __restrict__ idxbuf, float* __restrict__ out_q,
    float* __restrict__ out_idx_f, double* __restrict__ partials) {

    __shared__ double sred[4];
    int t  = threadIdx.x;
    int f4 = blockIdx.x * 256 + t;   // float4 index, 1024 blocks -> 262144 total
    int q  = f4 >> 4;                // 16 float4 per query row
    int c4 = f4 & 15;

    int k = idxbuf[q];
    float4 wv = reinterpret_cast<const float4*>(w)[k * 16 + c4];
    float4 xv = reinterpret_cast<const float4*>(x)[f4];

    float4 st;
    st.x = xv.x + (wv.x - xv.x);
    st.y = xv.y + (wv.y - xv.y);
    st.z = xv.z + (wv.z - xv.z);
    st.w = xv.w + (wv.w - xv.w);
    reinterpret_cast<float4*>(out_q)[f4] = st;

    if (c4 == 0) out_idx_f[q] = (float)k;

    double dx = (double)wv.x - (double)xv.x;
    double dy = (double)wv.y - (double)xv.y;
    double dz = (double)wv.z - (double)xv.z;
    double dw = (double)wv.w - (double)xv.w;
    double dsum = dx * dx + dy * dy + dz * dz + dw * dw;

#pragma unroll
    for (int off = 32; off; off >>= 1) dsum += __shfl_down(dsum, off);
    if ((t & 63) == 0) sred[t >> 6] = dsum;
    __syncthreads();
    if (t == 0) partials[blockIdx.x] = sred[0] + sred[1] + sred[2] + sred[3];
}

// ---------------------------------------------------------------------------
// Kernel 4: reduce partials -> loss = 1.25 * mean((q - x)^2)
// ---------------------------------------------------------------------------
__global__ __launch_bounds__(256) void loss_kernel(const double* __restrict__ partials,
                                                   float* __restrict__ out_loss) {
    __shared__ double sred[4];
    int t = threadIdx.x;
    double s = partials[t] + partials[t + 256] + partials[t + 512] + partials[t + 768];
#pragma unroll
    for (int off = 32; off; off >>= 1) s += __shfl_down(s, off);
    if ((t & 63) == 0) sred[t >> 6] = s;
    __syncthreads();
    if (t == 0) {
        double tot = sred[0] + sred[1] + sred[2] + sred[3];
        out_loss[0] = (float)(1.25 * tot / (double)(N_QUERIES * DIM));
    }
}

// ---------------------------------------------------------------------------
extern "C" void kernel_launch(void* const* d_in, const int* in_sizes, int n_in,
                              void* d_out, int out_size, void* d_ws, size_t ws_size,
                              hipStream_t stream) {
    const float* x = (const float*)d_in[0];   // inputs [16,32,32,64] f32
    const float* w = (const float*)d_in[1];   // weight [8192,64] f32
    float* out = (float*)d_out;

    char* ws = (char*)d_ws;
    float*  wsq      = (float*)ws;                       // 32 KB
    int*    idxbuf   = (int*)(ws + 32768);               // 64 KB
    double* partials = (double*)(ws + 32768 + 65536);    // 8 KB

    hipLaunchKernelGGL(wsq_kernel,    dim3(K_CODES / 256), dim3(256), 0, stream, w, wsq);
    hipLaunchKernelGGL(argmin_kernel, dim3(N_QUERIES / QT), dim3(256), 0, stream,
                       x, w, wsq, idxbuf);
    hipLaunchKernelGGL(gather_kernel, dim3(N_QUERIES * DIM / 1024), dim3(256), 0, stream,
                       x, w, idxbuf, out + 1, out + 1 + (size_t)N_QUERIES * DIM, partials);
    hipLaunchKernelGGL(loss_kernel,   dim3(1), dim3(256), 0, stream, partials, out);
}

// Round 3
// 160.765 us; speedup vs baseline: 33.6492x; 3.4197x over previous
//
#include <hip/hip_runtime.h>
#include <hip/hip_bf16.h>

#define N_QUERIES 16384
#define DIM 64
#define K_CODES 8192

#define KT 64                     // codes per LDS chunk
#define NCHUNK (K_CODES / KT)     // 128

typedef __attribute__((ext_vector_type(8))) short short8;
typedef __attribute__((ext_vector_type(4))) float f32x4;

// async global -> LDS, 16 B per lane (dest = wave-uniform base + lane*16)
__device__ __forceinline__ void gll16(const void* g, void* l) {
    __builtin_amdgcn_global_load_lds(
        (const __attribute__((address_space(1))) void*)g,
        (__attribute__((address_space(3))) void*)l, 16, 0, 0);
}

__device__ __forceinline__ unsigned short f2bf(float f) {   // RNE f32->bf16
    unsigned u = __float_as_uint(f);
    u += 0x7FFFu + ((u >> 16) & 1u);
    return (unsigned short)(u >> 16);
}
__device__ __forceinline__ float bf2f(unsigned short h) {
    return __uint_as_float(((unsigned)h) << 16);
}

// ---------------------------------------------------------------------------
// Kernel 1: prep codebook: wint[k] = [bf16(-2w) x64 | bf16(-2w - hi) x64],
// wsqp[k] = ||w_k||^2 + 2.0
// ---------------------------------------------------------------------------
__global__ __launch_bounds__(256) void prep_w(const float* __restrict__ w,
                                              unsigned short* __restrict__ wint,
                                              float* __restrict__ wsqp) {
    int k = blockIdx.x * 256 + threadIdx.x;   // 32 blocks
    const float4* w4 = reinterpret_cast<const float4*>(w + (size_t)k * DIM);
    unsigned short* row = wint + (size_t)k * 128;
    float s = 0.f;
#pragma unroll
    for (int i = 0; i < 16; ++i) {
        float4 v = w4[i];
        float fv[4] = {v.x, v.y, v.z, v.w};
#pragma unroll
        for (int e = 0; e < 4; ++e) {
            float f = fv[e];
            s = fmaf(f, f, s);
            float m = -2.f * f;
            unsigned short h = f2bf(m);
            unsigned short lo = f2bf(m - bf2f(h));
            row[i * 4 + e]      = h;
            row[64 + i * 4 + e] = lo;
        }
    }
    wsqp[k] = s + 2.0f;
}

// ---------------------------------------------------------------------------
// Kernel 2: MFMA argmin. Block = 256 thr (4 waves), 32 queries/block.
// Waves split each 64-code chunk into 4 16-code tiles. Per lane: top-2
// packed (truncated score | chunk) per owned query row; merge + f64 rescore.
// ---------------------------------------------------------------------------
__global__ __launch_bounds__(256) void argmin_mfma(
    const float* __restrict__ x, const float* __restrict__ w,
    const unsigned short* __restrict__ wint, const float* __restrict__ wsqp,
    int* __restrict__ out_idx) {

    __shared__ __align__(16) char lds[36864];
    // [0,16384)   dbuf parity 0   | after sweep: cand_p u32[32][128]
    // [16384,32768) dbuf parity 1 | after sweep: cand_c u32[32][128]
    // [32768,34816) red_v f64[32][8]; [34816,35840) red_i i32[32][8]

    const int t   = threadIdx.x;
    const int l   = t & 63;
    const int wv  = t >> 6;     // wave 0..3
    const int c_l = l & 15;     // col / local-row selector
    const int kb  = l >> 4;     // k-group 0..3
    const int qb  = blockIdx.x * 32;

    // ---- A fragments: xh/xl for 2 rowtiles x 2 k-windows, built in-reg ----
    short8 axh[2][2], axl[2][2];
#pragma unroll
    for (int rt = 0; rt < 2; ++rt)
#pragma unroll
        for (int win = 0; win < 2; ++win) {
            int q = qb + rt * 16 + c_l;
            const float* xr = x + (size_t)q * DIM + win * 32 + kb * 8;
            float fv[8];
            *reinterpret_cast<float4*>(&fv[0]) = *reinterpret_cast<const float4*>(xr);
            *reinterpret_cast<float4*>(&fv[4]) = *reinterpret_cast<const float4*>(xr + 4);
#pragma unroll
            for (int e = 0; e < 8; ++e) {
                unsigned short h = f2bf(fv[e]);
                axh[rt][win][e] = (short)h;
                axl[rt][win][e] = (short)f2bf(fv[e] - bf2f(h));
            }
        }

    // ---- stage chunk 0 ----
    {
        const char* src = (const char*)wint;
#pragma unroll
        for (int i = 0; i < 4; ++i) {
            int P = i * 256 + t;
            int code = P >> 4, ps = P & 15;
            int lslot = ps ^ (code & 7);
            gll16(src + code * 256 + lslot * 16, lds + P * 16);
        }
    }
    float wsq_cur = wsqp[wv * 16 + c_l];
    asm volatile("s_waitcnt vmcnt(0)" ::: "memory");
    __syncthreads();

    unsigned p1[8], p2[8];
#pragma unroll
    for (int i = 0; i < 8; ++i) { p1[i] = 0xFFFFFFFFu; p2[i] = 0xFFFFFFFFu; }

    const unsigned LOWMASK = 0x7Fu;
    const int lc  = wv * 16 + c_l;      // local code row in chunk
    const int swz = lc & 7;

    for (int c = 0; c < NCHUNK; ++c) {
        // issue next chunk's staging (opposite parity; in flight during MFMA)
        if (c + 1 < NCHUNK) {
            const char* src = (const char*)wint + (size_t)(c + 1) * 16384;
            char* dst = lds + ((c + 1) & 1) * 16384;
#pragma unroll
            for (int i = 0; i < 4; ++i) {
                int P = i * 256 + t;
                int code = P >> 4, ps = P & 15;
                int lslot = ps ^ (code & 7);
                gll16(src + code * 256 + lslot * 16, dst + P * 16);
            }
        }
        float wsq_nxt = wsqp[((c + 1) & 127) * 64 + wv * 16 + c_l];

        const char* rowp = lds + (c & 1) * 16384 + lc * 256;
        short8 bh0 = *reinterpret_cast<const short8*>(rowp + ((kb     ) ^ swz) * 16);
        short8 bh1 = *reinterpret_cast<const short8*>(rowp + ((kb +  4) ^ swz) * 16);
        short8 bl0 = *reinterpret_cast<const short8*>(rowp + ((kb +  8) ^ swz) * 16);
        short8 bl1 = *reinterpret_cast<const short8*>(rowp + ((kb + 12) ^ swz) * 16);

        f32x4 z = {0.f, 0.f, 0.f, 0.f};
        f32x4 d0, d1;
        d0 = __builtin_amdgcn_mfma_f32_16x16x32_bf16(axh[0][0], bh0, z, 0, 0, 0);
        d0 = __builtin_amdgcn_mfma_f32_16x16x32_bf16(axh[0][1], bh1, d0, 0, 0, 0);
        d0 = __builtin_amdgcn_mfma_f32_16x16x32_bf16(axl[0][0], bh0, d0, 0, 0, 0);
        d0 = __builtin_amdgcn_mfma_f32_16x16x32_bf16(axl[0][1], bh1, d0, 0, 0, 0);
        d0 = __builtin_amdgcn_mfma_f32_16x16x32_bf16(axh[0][0], bl0, d0, 0, 0, 0);
        d0 = __builtin_amdgcn_mfma_f32_16x16x32_bf16(axh[0][1], bl1, d0, 0, 0, 0);
        d1 = __builtin_amdgcn_mfma_f32_16x16x32_bf16(axh[1][0], bh0, z, 0, 0, 0);
        d1 = __builtin_amdgcn_mfma_f32_16x16x32_bf16(axh[1][1], bh1, d1, 0, 0, 0);
        d1 = __builtin_amdgcn_mfma_f32_16x16x32_bf16(axl[1][0], bh0, d1, 0, 0, 0);
        d1 = __builtin_amdgcn_mfma_f32_16x16x32_bf16(axl[1][1], bh1, d1, 0, 0, 0);
        d1 = __builtin_amdgcn_mfma_f32_16x16x32_bf16(axh[1][0], bl0, d1, 0, 0, 0);
        d1 = __builtin_amdgcn_mfma_f32_16x16x32_bf16(axh[1][1], bl1, d1, 0, 0, 0);

        unsigned relx = (unsigned)c;
#pragma unroll
        for (int i = 0; i < 8; ++i) {
            float s = ((i < 4) ? d0[i & 3] : d1[i & 3]) + wsq_cur;
            unsigned bits = __float_as_uint(s);
            unsigned p, pm;
            asm("v_bfi_b32 %0, %1, %2, %3" : "=v"(p) : "s"(LOWMASK), "v"(relx), "v"(bits));
            asm("v_med3_u32 %0, %1, %2, %3" : "=v"(pm) : "v"(p), "v"(p1[i]), "v"(p2[i]));
            p1[i] = (p < p1[i]) ? p : p1[i];
            p2[i] = pm;
        }

        asm volatile("s_waitcnt vmcnt(0)" ::: "memory");
        __syncthreads();
        wsq_cur = wsq_nxt;
    }

    // ---- candidate merge: dbuf is dead, alias as cand arrays ----
    unsigned* cand_p = reinterpret_cast<unsigned*>(lds);
    unsigned* cand_c = reinterpret_cast<unsigned*>(lds + 16384);
#pragma unroll
    for (int i = 0; i < 8; ++i) {
        int rt = i >> 2, j = i & 3;
        int row = rt * 16 + kb * 4 + j;
        int slot = wv * 32 + c_l * 2;
        unsigned P1 = p1[i], P2 = p2[i];
        cand_p[row * 128 + slot]     = P1;
        cand_p[row * 128 + slot + 1] = P2;
        cand_c[row * 128 + slot]     = (P1 & 0x7Fu) * 64u + wv * 16 + c_l;
        cand_c[row * 128 + slot + 1] = (P2 & 0x7Fu) * 64u + wv * 16 + c_l;
    }
    __syncthreads();

    double* red_v = reinterpret_cast<double*>(lds + 32768);
    int*    red_i = reinterpret_cast<int*>(lds + 34816);
    {
        int row = t >> 3, sc = t & 7;
        unsigned b1 = 0xFFFFFFFFu, b2 = 0xFFFFFFFFu;
        int c1 = 0x7fffffff, c2 = 0x7fffffff;
#pragma unroll 1
        for (int s = 0; s < 16; ++s) {
            unsigned p = cand_p[row * 128 + sc * 16 + s];
            int      cc = (int)cand_c[row * 128 + sc * 16 + s];
            bool beats1 = (p < b1) || (p == b1 && cc < c1);
            bool beats2 = (p < b2) || (p == b2 && cc < c2);
            if (beats1) { b2 = b1; c2 = c1; b1 = p; c1 = cc; }
            else if (beats2) { b2 = p; c2 = cc; }
        }
        int q = qb + row;
        const float* xr = x + (size_t)q * DIM;
        double bv = 1e300; int bi = 0x7fffffff;
#pragma unroll 1
        for (int cnd = 0; cnd < 2; ++cnd) {
            int k = (cnd == 0) ? c1 : c2;
            const float* wr = w + (size_t)k * DIM;
            double dot = 0.0, w2 = 0.0;
#pragma unroll
            for (int d = 0; d < DIM; d += 4) {
                float4 wv4 = *reinterpret_cast<const float4*>(wr + d);
                float4 xv4 = *reinterpret_cast<const float4*>(xr + d);
                dot += (double)xv4.x * wv4.x + (double)xv4.y * wv4.y
                     + (double)xv4.z * wv4.z + (double)xv4.w * wv4.w;
                w2  += (double)wv4.x * wv4.x + (double)wv4.y * wv4.y
                     + (double)wv4.z * wv4.z + (double)wv4.w * wv4.w;
            }
            double s = w2 - 2.0 * dot;
            if (s < bv || (s == bv && k < bi)) { bv = s; bi = k; }
        }
        red_v[row * 8 + sc] = bv;
        red_i[row * 8 + sc] = bi;
    }
    __syncthreads();

    if (t < 32) {
        double bv = red_v[t * 8];
        int    bi = red_i[t * 8];
#pragma unroll 1
        for (int s = 1; s < 8; ++s) {
            double v  = red_v[t * 8 + s];
            int    ii = red_i[t * 8 + s];
            if (v < bv || (v == bv && ii < bi)) { bv = v; bi = ii; }
        }
        out_idx[qb + t] = bi;
    }
}

// ---------------------------------------------------------------------------
// Kernel 3: gather codebook rows, write quantized_st + indices-as-float,
// accumulate per-block f64 partial sums of (q - x)^2.
// ---------------------------------------------------------------------------
__global__ __launch_bounds__(256) void gather_kernel(
    const float* __restrict__ x, const float* __restrict__ w,
    const int* __restrict__ idxbuf, float* __restrict__ out_q,
    float* __restrict__ out_idx_f, double* __restrict__ partials) {

    __shared__ double sred[4];
    int t  = threadIdx.x;
    int f4 = blockIdx.x * 256 + t;
    int q  = f4 >> 4;
    int c4 = f4 & 15;

    int k = idxbuf[q];
    float4 wv = reinterpret_cast<const float4*>(w)[k * 16 + c4];
    float4 xv = reinterpret_cast<const float4*>(x)[f4];

    float4 st;
    st.x = xv.x + (wv.x - xv.x);
    st.y = xv.y + (wv.y - xv.y);
    st.z = xv.z + (wv.z - xv.z);
    st.w = xv.w + (wv.w - xv.w);
    reinterpret_cast<float4*>(out_q)[f4] = st;

    if (c4 == 0) out_idx_f[q] = (float)k;

    double dx = (double)wv.x - (double)xv.x;
    double dy = (double)wv.y - (double)xv.y;
    double dz = (double)wv.z - (double)xv.z;
    double dw = (double)wv.w - (double)xv.w;
    double dsum = dx * dx + dy * dy + dz * dz + dw * dw;

#pragma unroll
    for (int off = 32; off; off >>= 1) dsum += __shfl_down(dsum, off);
    if ((t & 63) == 0) sred[t >> 6] = dsum;
    __syncthreads();
    if (t == 0) partials[blockIdx.x] = sred[0] + sred[1] + sred[2] + sred[3];
}

// ---------------------------------------------------------------------------
// Kernel 4: reduce partials -> loss = 1.25 * mean((q - x)^2)
// ---------------------------------------------------------------------------
__global__ __launch_bounds__(256) void loss_kernel(const double* __restrict__ partials,
                                                   float* __restrict__ out_loss) {
    __shared__ double sred[4];
    int t = threadIdx.x;
    double s = partials[t] + partials[t + 256] + partials[t + 512] + partials[t + 768];
#pragma unroll
    for (int off = 32; off; off >>= 1) s += __shfl_down(s, off);
    if ((t & 63) == 0) sred[t >> 6] = s;
    __syncthreads();
    if (t == 0) {
        double tot = sred[0] + sred[1] + sred[2] + sred[3];
        out_loss[0] = (float)(1.25 * tot / (double)(N_QUERIES * DIM));
    }
}

// ---------------------------------------------------------------------------
extern "C" void kernel_launch(void* const* d_in, const int* in_sizes, int n_in,
                              void* d_out, int out_size, void* d_ws, size_t ws_size,
                              hipStream_t stream) {
    const float* x = (const float*)d_in[0];   // [16,32,32,64] f32
    const float* w = (const float*)d_in[1];   // [8192,64] f32
    float* out = (float*)d_out;

    char* ws = (char*)d_ws;
    unsigned short* wint = (unsigned short*)ws;                    // 2 MB
    float*  wsqp     = (float*)(ws + 2097152);                     // 32 KB
    int*    idxbuf   = (int*)(ws + 2097152 + 32768);               // 64 KB
    double* partials = (double*)(ws + 2097152 + 32768 + 65536);    // 8 KB

    hipLaunchKernelGGL(prep_w,      dim3(32),   dim3(256), 0, stream, w, wint, wsqp);
    hipLaunchKernelGGL(argmin_mfma, dim3(512),  dim3(256), 0, stream, x, w, wint, wsqp, idxbuf);
    hipLaunchKernelGGL(gather_kernel, dim3(1024), dim3(256), 0, stream,
                       x, w, idxbuf, out + 1, out + 1 + (size_t)N_QUERIES * DIM, partials);
    hipLaunchKernelGGL(loss_kernel, dim3(1), dim3(256), 0, stream, partials, out);
}

// Round 4
// 141.702 us; speedup vs baseline: 38.1760x; 1.1345x over previous
//
#include <hip/hip_runtime.h>
#include <hip/hip_bf16.h>

#define N_QUERIES 16384
#define DIM 64
#define K_CODES 8192

#define QT 64                 // queries per block (argmin kernel)
#define KT 64                 // codes per LDS chunk
#define NCHH 64               // chunks per half-codebook sweep

typedef __attribute__((ext_vector_type(8))) short short8;
typedef __attribute__((ext_vector_type(4))) float f32x4;

// async global -> LDS, 16 B per lane (dest = wave-uniform base + lane*16)
__device__ __forceinline__ void gll16(const void* g, void* l) {
    __builtin_amdgcn_global_load_lds(
        (const __attribute__((address_space(1))) void*)g,
        (__attribute__((address_space(3))) void*)l, 16, 0, 0);
}

__device__ __forceinline__ unsigned short f2bf(float f) {   // RNE f32->bf16
    unsigned u = __float_as_uint(f);
    u += 0x7FFFu + ((u >> 16) & 1u);
    return (unsigned short)(u >> 16);
}
__device__ __forceinline__ float bf2f(unsigned short h) {
    return __uint_as_float(((unsigned)h) << 16);
}

// ---------------------------------------------------------------------------
// Kernel 1: prep codebook: wint[k] = [bf16(-2w) x64 | bf16(-2w - hi) x64],
// wsqp[k] = ||w_k||^2 + 3.0  (bias keeps packed scores strictly positive)
// ---------------------------------------------------------------------------
__global__ __launch_bounds__(256) void prep_w(const float* __restrict__ w,
                                              unsigned short* __restrict__ wint,
                                              float* __restrict__ wsqp) {
    int k = blockIdx.x * 256 + threadIdx.x;   // 32 blocks
    const float4* w4 = reinterpret_cast<const float4*>(w + (size_t)k * DIM);
    unsigned short* row = wint + (size_t)k * 128;
    float s = 0.f;
#pragma unroll
    for (int i = 0; i < 16; ++i) {
        float4 v = w4[i];
        float fv[4] = {v.x, v.y, v.z, v.w};
#pragma unroll
        for (int e = 0; e < 4; ++e) {
            float f = fv[e];
            s = fmaf(f, f, s);
            float m = -2.f * f;
            unsigned short h = f2bf(m);
            unsigned short lo = f2bf(m - bf2f(h));
            row[i * 4 + e]      = h;
            row[64 + i * 4 + e] = lo;
        }
    }
    wsqp[k] = s + 3.0f;
}

// ---------------------------------------------------------------------------
// Kernel 2: MFMA argmin over one half of the codebook per block.
// Block = 256 thr (4 waves), 64 queries, half = 4096 codes (64 chunks of 64).
// 8 independent MFMA chains of depth 3 per chunk; wsq folded into C-init.
// Per-lane top-2 packed (score|chunk) per (query,slot); block merge + f64
// rescore; writes exact (f64 val, idx) per (query, half).
// ---------------------------------------------------------------------------
__global__ __launch_bounds__(256, 2) void argmin_mfma(
    const float* __restrict__ x, const float* __restrict__ w,
    const unsigned short* __restrict__ wint, const float* __restrict__ wsqp,
    double* __restrict__ val2, int* __restrict__ idx2) {

    __shared__ __align__(16) char lds[35840];
    // [0,32768)     dbuf (2 x 16 KB)  | after sweep: cand u32[64][128]
    // [32768,34816) red_v f64[64][4]
    // [34816,35840) red_i i32[64][4]

    const int t   = threadIdx.x;
    const int l   = t & 63;
    const int wv  = t >> 6;     // wave 0..3
    const int c_l = l & 15;
    const int kb  = l >> 4;     // k-group 0..3
    const int bq  = blockIdx.x >> 1;
    const int h   = blockIdx.x & 1;
    const int qb  = bq * QT;
    const char* wbase = (const char*)wint + (size_t)h * 4096 * 256;

    // ---- A fragments: xh/xl for 4 rowtiles x 2 k-windows, built in-reg ----
    short8 axh[4][2], axl[4][2];
#pragma unroll
    for (int rt = 0; rt < 4; ++rt)
#pragma unroll
        for (int win = 0; win < 2; ++win) {
            int q = qb + rt * 16 + c_l;
            const float* xr = x + (size_t)q * DIM + win * 32 + kb * 8;
            float fv[8];
            *reinterpret_cast<float4*>(&fv[0]) = *reinterpret_cast<const float4*>(xr);
            *reinterpret_cast<float4*>(&fv[4]) = *reinterpret_cast<const float4*>(xr + 4);
#pragma unroll
            for (int e = 0; e < 8; ++e) {
                unsigned short hh = f2bf(fv[e]);
                axh[rt][win][e] = (short)hh;
                axl[rt][win][e] = (short)f2bf(fv[e] - bf2f(hh));
            }
        }

    // ---- stage chunk 0 ----
#pragma unroll
    for (int i = 0; i < 4; ++i) {
        int P = i * 256 + t;
        int code = P >> 4, ps = P & 15;
        int lslot = ps ^ (code & 7);
        gll16(wbase + code * 256 + lslot * 16, lds + P * 16);
    }
    const int lc  = wv * 16 + c_l;          // local code row in chunk
    const int swz = c_l & 7;                // == lc & 7
    float wsq_cur = wsqp[h * 4096 + lc];
    asm volatile("s_waitcnt vmcnt(0)" ::: "memory");
    __syncthreads();

    unsigned p1[16], p2[16];
#pragma unroll
    for (int i = 0; i < 16; ++i) { p1[i] = 0xFFFFFFFFu; p2[i] = 0xFFFFFFFFu; }
    const unsigned LOWMASK = 0x3Fu;

    for (int c = 0; c < NCHH; ++c) {
        if (c + 1 < NCHH) {
            const char* src = wbase + (size_t)(c + 1) * 16384;
            char* dst = lds + ((c + 1) & 1) * 16384;
#pragma unroll
            for (int i = 0; i < 4; ++i) {
                int P = i * 256 + t;
                int code = P >> 4, ps = P & 15;
                int lslot = ps ^ (code & 7);
                gll16(src + code * 256 + lslot * 16, dst + P * 16);
            }
        }
        float wsq_nxt = wsqp[h * 4096 + ((c + 1) & 63) * 64 + lc];

        const char* rowp = lds + (c & 1) * 16384 + lc * 256;
        short8 bh0 = *reinterpret_cast<const short8*>(rowp + ((kb     ) ^ swz) * 16);
        short8 bh1 = *reinterpret_cast<const short8*>(rowp + ((kb +  4) ^ swz) * 16);
        short8 bl0 = *reinterpret_cast<const short8*>(rowp + ((kb +  8) ^ swz) * 16);
        short8 bl1 = *reinterpret_cast<const short8*>(rowp + ((kb + 12) ^ swz) * 16);

        f32x4 wsqv = {wsq_cur, wsq_cur, wsq_cur, wsq_cur};
        f32x4 z    = {0.f, 0.f, 0.f, 0.f};
        f32x4 acc[8];
        // 8 independent chains of depth 3 (acc[rt] = P-chain, acc[4+rt] = Q)
#pragma unroll
        for (int rt = 0; rt < 4; ++rt) {
            acc[rt]     = __builtin_amdgcn_mfma_f32_16x16x32_bf16(axh[rt][0], bh0, wsqv, 0, 0, 0);
            acc[4 + rt] = __builtin_amdgcn_mfma_f32_16x16x32_bf16(axl[rt][1], bh1, z,    0, 0, 0);
        }
#pragma unroll
        for (int rt = 0; rt < 4; ++rt) {
            acc[rt]     = __builtin_amdgcn_mfma_f32_16x16x32_bf16(axh[rt][1], bh1, acc[rt],     0, 0, 0);
            acc[4 + rt] = __builtin_amdgcn_mfma_f32_16x16x32_bf16(axh[rt][0], bl0, acc[4 + rt], 0, 0, 0);
        }
#pragma unroll
        for (int rt = 0; rt < 4; ++rt) {
            acc[rt]     = __builtin_amdgcn_mfma_f32_16x16x32_bf16(axl[rt][0], bh0, acc[rt],     0, 0, 0);
            acc[4 + rt] = __builtin_amdgcn_mfma_f32_16x16x32_bf16(axh[rt][1], bl1, acc[4 + rt], 0, 0, 0);
        }

        unsigned relx = (unsigned)c;
#pragma unroll
        for (int i = 0; i < 16; ++i) {
            int rt = i >> 2, r = i & 3;
            float s = acc[rt][r] + acc[4 + rt][r];
            unsigned bits = __float_as_uint(s);
            unsigned p, pm;
            asm("v_bfi_b32 %0, %1, %2, %3" : "=v"(p) : "s"(LOWMASK), "v"(relx), "v"(bits));
            asm("v_med3_u32 %0, %1, %2, %3" : "=v"(pm) : "v"(p), "v"(p1[i]), "v"(p2[i]));
            p1[i] = (p < p1[i]) ? p : p1[i];
            p2[i] = pm;
        }

        asm volatile("s_waitcnt vmcnt(0)" ::: "memory");
        __syncthreads();
        wsq_cur = wsq_nxt;
    }

    // ---- candidate write: dbuf is dead, alias as cand[64][128] ----
    unsigned* cand = reinterpret_cast<unsigned*>(lds);
#pragma unroll
    for (int i = 0; i < 16; ++i) {
        int rt = i >> 2, r = i & 3;
        int row  = rt * 16 + kb * 4 + r;
        int slot = wv * 32 + c_l * 2;
        cand[row * 128 + slot]     = p1[i];
        cand[row * 128 + slot + 1] = p2[i];
    }
    __syncthreads();

    double* red_v = reinterpret_cast<double*>(lds + 32768);
    int*    red_i = reinterpret_cast<int*>(lds + 34816);
    {
        int row = t >> 2, sc = t & 3;   // 4 scanners per query row
        unsigned b1 = 0xFFFFFFFFu, b2 = 0xFFFFFFFFu;
        int c1 = 0x7fffffff, c2 = 0x7fffffff;
#pragma unroll 1
        for (int s = 0; s < 32; ++s) {
            int slot = sc * 32 + s;
            unsigned p = cand[row * 128 + slot];
            int cc = ((int)(p & 0x3Fu)) * 64 + sc * 16 + ((slot >> 1) & 15);
            bool beats1 = (p < b1) || (p == b1 && cc < c1);
            bool beats2 = (p < b2) || (p == b2 && cc < c2);
            if (beats1) { b2 = b1; c2 = c1; b1 = p; c1 = cc; }
            else if (beats2) { b2 = p; c2 = cc; }
        }
        int q = qb + row;
        const float* xr = x + (size_t)q * DIM;
        double bv = 1e300; int bi = 0x7fffffff;
#pragma unroll 1
        for (int cnd = 0; cnd < 2; ++cnd) {
            int k = h * 4096 + ((cnd == 0) ? c1 : c2);
            const float* wr = w + (size_t)k * DIM;
            double dot = 0.0, w2 = 0.0;
#pragma unroll
            for (int d = 0; d < DIM; d += 4) {
                float4 wv4 = *reinterpret_cast<const float4*>(wr + d);
                float4 xv4 = *reinterpret_cast<const float4*>(xr + d);
                dot += (double)xv4.x * wv4.x + (double)xv4.y * wv4.y
                     + (double)xv4.z * wv4.z + (double)xv4.w * wv4.w;
                w2  += (double)wv4.x * wv4.x + (double)wv4.y * wv4.y
                     + (double)wv4.z * wv4.z + (double)wv4.w * wv4.w;
            }
            double s = w2 - 2.0 * dot;
            if (s < bv || (s == bv && k < bi)) { bv = s; bi = k; }
        }
        red_v[row * 4 + sc] = bv;
        red_i[row * 4 + sc] = bi;
    }
    __syncthreads();

    if (t < QT) {
        double bv = red_v[t * 4];
        int    bi = red_i[t * 4];
#pragma unroll 1
        for (int s = 1; s < 4; ++s) {
            double v  = red_v[t * 4 + s];
            int    ii = red_i[t * 4 + s];
            if (v < bv || (v == bv && ii < bi)) { bv = v; bi = ii; }
        }
        int q = qb + t;
        val2[q * 2 + h] = bv;
        idx2[q * 2 + h] = bi;
    }
}

// ---------------------------------------------------------------------------
// Kernel 3: merge halves inline, gather codebook rows, write quantized_st +
// indices-as-float, accumulate per-block f64 partial sums of (q - x)^2.
// ---------------------------------------------------------------------------
__global__ __launch_bounds__(256) void gather_kernel(
    const float* __restrict__ x, const float* __restrict__ w,
    const double* __restrict__ val2, const int* __restrict__ idx2,
    float* __restrict__ out_q, float* __restrict__ out_idx_f,
    double* __restrict__ partials) {

    __shared__ double sred[4];
    int t  = threadIdx.x;
    int f4 = blockIdx.x * 256 + t;
    int q  = f4 >> 4;
    int c4 = f4 & 15;

    double v0 = val2[q * 2], v1 = val2[q * 2 + 1];
    int    k0 = idx2[q * 2], k1 = idx2[q * 2 + 1];
    int k = (v0 < v1 || (v0 == v1 && k0 < k1)) ? k0 : k1;

    float4 wv = reinterpret_cast<const float4*>(w)[k * 16 + c4];
    float4 xv = reinterpret_cast<const float4*>(x)[f4];

    float4 st;
    st.x = xv.x + (wv.x - xv.x);
    st.y = xv.y + (wv.y - xv.y);
    st.z = xv.z + (wv.z - xv.z);
    st.w = xv.w + (wv.w - xv.w);
    reinterpret_cast<float4*>(out_q)[f4] = st;

    if (c4 == 0) out_idx_f[q] = (float)k;

    double dx = (double)wv.x - (double)xv.x;
    double dy = (double)wv.y - (double)xv.y;
    double dz = (double)wv.z - (double)xv.z;
    double dw = (double)wv.w - (double)xv.w;
    double dsum = dx * dx + dy * dy + dz * dz + dw * dw;

#pragma unroll
    for (int off = 32; off; off >>= 1) dsum += __shfl_down(dsum, off);
    if ((t & 63) == 0) sred[t >> 6] = dsum;
    __syncthreads();
    if (t == 0) partials[blockIdx.x] = sred[0] + sred[1] + sred[2] + sred[3];
}

// ---------------------------------------------------------------------------
// Kernel 4: reduce partials -> loss = 1.25 * mean((q - x)^2)
// ---------------------------------------------------------------------------
__global__ __launch_bounds__(256) void loss_kernel(const double* __restrict__ partials,
                                                   float* __restrict__ out_loss) {
    __shared__ double sred[4];
    int t = threadIdx.x;
    double s = partials[t] + partials[t + 256] + partials[t + 512] + partials[t + 768];
#pragma unroll
    for (int off = 32; off; off >>= 1) s += __shfl_down(s, off);
    if ((t & 63) == 0) sred[t >> 6] = s;
    __syncthreads();
    if (t == 0) {
        double tot = sred[0] + sred[1] + sred[2] + sred[3];
        out_loss[0] = (float)(1.25 * tot / (double)(N_QUERIES * DIM));
    }
}

// ---------------------------------------------------------------------------
extern "C" void kernel_launch(void* const* d_in, const int* in_sizes, int n_in,
                              void* d_out, int out_size, void* d_ws, size_t ws_size,
                              hipStream_t stream) {
    const float* x = (const float*)d_in[0];   // [16,32,32,64] f32
    const float* w = (const float*)d_in[1];   // [8192,64] f32
    float* out = (float*)d_out;

    char* ws = (char*)d_ws;
    unsigned short* wint = (unsigned short*)ws;                      // 2 MB
    float*  wsqp     = (float*)(ws + 2097152);                       // 32 KB
    double* val2     = (double*)(ws + 2097152 + 32768);              // 256 KB
    int*    idx2     = (int*)(ws + 2097152 + 32768 + 262144);        // 128 KB
    double* partials = (double*)(ws + 2097152 + 32768 + 262144 + 131072);  // 8 KB

    hipLaunchKernelGGL(prep_w,      dim3(32),  dim3(256), 0, stream, w, wint, wsqp);
    hipLaunchKernelGGL(argmin_mfma, dim3(512), dim3(256), 0, stream, x, w, wint, wsqp, val2, idx2);
    hipLaunchKernelGGL(gather_kernel, dim3(1024), dim3(256), 0, stream,
                       x, w, val2, idx2, out + 1, out + 1 + (size_t)N_QUERIES * DIM, partials);
    hipLaunchKernelGGL(loss_kernel, dim3(1), dim3(256), 0, stream, partials, out);
}